// Round 5
// baseline (32723.380 us; speedup 1.0000x reference)
//
#include <hip/hip_runtime.h>

// Problem dims
#define B_N 4096
#define V_N 2000
#define K_N 50
#define H_N 500
#define E_N 300
#define VP  2048   // padded vocab (mult of 32 for MFMA k)
#define TP  64     // padded topics
#define SK_NWG 32
#define SK_BLK 512
#define SK_ITER 500
#define RED_STRIDE 68          // floats; pad 64->68 kills LDS bank conflicts
#define RED_WAVE   (64 * RED_STRIDE)          // 4352 floats per wave buffer
#define SK_LDS     (8 * RED_WAVE * 4 + 64 * RED_STRIDE * 2)  // 139264 + 8704 = 147968

typedef short bf16x8 __attribute__((ext_vector_type(8)));
typedef float f32x4n __attribute__((ext_vector_type(4)));

__device__ __forceinline__ unsigned short f2bf(float f) {
  unsigned int x = __float_as_uint(f);
  x = (x + 0x7FFFu + ((x >> 16) & 1u)) >> 16;
  return (unsigned short)x;
}
__device__ __forceinline__ float bf2f(unsigned short h) {
  return __uint_as_float((unsigned int)h << 16);
}
__device__ __forceinline__ float softplusf(float x) {
  return fmaxf(x, 0.f) + log1pf(expf(-fabsf(x)));
}

// Agent-coherent 16B load as two 8B relaxed atomics (bypass non-coherent L2,
// serviced at the coherence point). Used ONLY for u/v.
__device__ __forceinline__ bf16x8 coh_load8(const unsigned short* p) {
  unsigned long long lo = __hip_atomic_load((const unsigned long long*)p,
                                            __ATOMIC_RELAXED, __HIP_MEMORY_SCOPE_AGENT);
  unsigned long long hi = __hip_atomic_load((const unsigned long long*)(p + 4),
                                            __ATOMIC_RELAXED, __HIP_MEMORY_SCOPE_AGENT);
  union { unsigned long long u[2]; bf16x8 v; } cvt;
  cvt.u[0] = lo; cvt.u[1] = hi;
  return cvt.v;
}
__device__ __forceinline__ void coh_store8(unsigned short* p, ushort4 val) {
  union { ushort4 s; unsigned long long u; } cvt; cvt.s = val;
  __hip_atomic_store((unsigned long long*)p, cvt.u,
                     __ATOMIC_RELAXED, __HIP_MEMORY_SCOPE_AGENT);
}

// ---------------------------------------------------------------------------
// fp32 tiled GEMM: C = act(A(MxK) @ B(KxN) + bias); act: 0 none, 1 softplus
// ---------------------------------------------------------------------------
__global__ __launch_bounds__(256) void gemm_nn_kern(
    const float* __restrict__ A, const float* __restrict__ Bm,
    const float* __restrict__ bias, void* __restrict__ Cv,
    int M, int N, int Kd, int act, int bf16out) {
  __shared__ float As[16][68];
  __shared__ float Bs[16][68];
  const int tid = threadIdx.x;
  const int tx = tid & 15, ty = tid >> 4;
  const int row0 = (int)blockIdx.y * 64, col0 = (int)blockIdx.x * 64;
  float acc[4][4];
#pragma unroll
  for (int i = 0; i < 4; ++i)
#pragma unroll
    for (int j = 0; j < 4; ++j) acc[i][j] = 0.f;

  for (int k0 = 0; k0 < Kd; k0 += 16) {
#pragma unroll
    for (int i = 0; i < 4; ++i) {
      int id = tid + 256 * i;
      int m = id >> 4, kk = id & 15;
      int gr = row0 + m, gk = k0 + kk;
      As[kk][m] = (gr < M && gk < Kd) ? A[(size_t)gr * Kd + gk] : 0.f;
    }
#pragma unroll
    for (int i = 0; i < 4; ++i) {
      int id = tid + 256 * i;
      int kk = id >> 6, n = id & 63;
      int gk = k0 + kk, gc = col0 + n;
      Bs[kk][n] = (gk < Kd && gc < N) ? Bm[(size_t)gk * N + gc] : 0.f;
    }
    __syncthreads();
#pragma unroll
    for (int kk = 0; kk < 16; ++kk) {
      float4 av = *(const float4*)&As[kk][ty * 4];
      float4 bv = *(const float4*)&Bs[kk][tx * 4];
      float aa[4] = {av.x, av.y, av.z, av.w};
      float bb[4] = {bv.x, bv.y, bv.z, bv.w};
#pragma unroll
      for (int i = 0; i < 4; ++i)
#pragma unroll
        for (int j = 0; j < 4; ++j) acc[i][j] = fmaf(aa[i], bb[j], acc[i][j]);
    }
    __syncthreads();
  }
#pragma unroll
  for (int i = 0; i < 4; ++i) {
    int row = row0 + ty * 4 + i;
    if (row >= M) continue;
#pragma unroll
    for (int j = 0; j < 4; ++j) {
      int col = col0 + tx * 4 + j;
      if (col >= N) continue;
      float v = acc[i][j] + (bias ? bias[col] : 0.f);
      if (act) v = softplusf(v);
      if (bf16out) ((unsigned short*)Cv)[(size_t)row * N + col] = f2bf(v);
      else         ((float*)Cv)[(size_t)row * N + col] = v;
    }
  }
}

// ---------------------------------------------------------------------------
// Column partial sums (BN stats)
// ---------------------------------------------------------------------------
__global__ void colstats2_kern(const float* __restrict__ X, int C, int rowsPer,
                               float* __restrict__ sums, float* __restrict__ sumsq) {
  int c = (int)blockIdx.x * 256 + threadIdx.x;
  if (c >= C) return;
  int r0 = (int)blockIdx.y * rowsPer;
  float s = 0.f, s2 = 0.f;
  for (int r = r0; r < r0 + rowsPer; ++r) {
    float v = X[(size_t)r * C + c];
    s += v; s2 += v * v;
  }
  atomicAdd(&sums[c], s);
  atomicAdd(&sumsq[c], s2);
}

__global__ void colstats2_bf_kern(const unsigned short* __restrict__ X, int C, int rowsPer,
                                  float* __restrict__ sums, float* __restrict__ sumsq) {
  int c = (int)blockIdx.x * 256 + threadIdx.x;
  if (c >= C) return;
  int r0 = (int)blockIdx.y * rowsPer;
  float s = 0.f, s2 = 0.f;
  for (int r = r0; r < r0 + rowsPer; ++r) {
    float v = bf2f(X[(size_t)r * C + c]);
    s += v; s2 += v * v;
  }
  atomicAdd(&sums[c], s);
  atomicAdd(&sumsq[c], s2);
}

__global__ void finstats_kern(const float* __restrict__ sums, const float* __restrict__ sumsq,
                              int C, float invM, float* __restrict__ mean,
                              float* __restrict__ rstd) {
  int c = (int)blockIdx.x * 256 + threadIdx.x;
  if (c >= C) return;
  float mu = sums[c] * invM;
  float var = sumsq[c] * invM - mu * mu;
  mean[c] = mu;
  rstd[c] = rsqrtf(var + 1e-5f);
}

// ---------------------------------------------------------------------------
// BN-apply + reparam + row-softmax(50) -> theta ; accumulate KLD
// ---------------------------------------------------------------------------
__global__ __launch_bounds__(256) void reparam_kern(
    const float* __restrict__ MUp, const float* __restrict__ LVp,
    const float* __restrict__ mmean, const float* __restrict__ mrstd,
    const float* __restrict__ lmean, const float* __restrict__ lrstd,
    const float* __restrict__ mbn, const float* __restrict__ lbn,
    const float* __restrict__ epsb, float* __restrict__ TH,
    float* __restrict__ accp) {
  const int wave = threadIdx.x >> 6, lane = threadIdx.x & 63;
  const int row = (int)blockIdx.x * 4 + wave;
  const bool act = lane < K_N;
  float mu = 0.f, lv = 0.f, z = 0.f;
  size_t base = (size_t)row * K_N + lane;
  if (act) {
    mu = (MUp[base] - mmean[lane]) * mrstd[lane] + mbn[lane];
    lv = (LVp[base] - lmean[lane]) * lrstd[lane] + lbn[lane];
    z = mu + expf(0.5f * lv) * epsb[base];
  }
  float zm = act ? z : -1e30f;
#pragma unroll
  for (int m = 32; m; m >>= 1) zm = fmaxf(zm, __shfl_xor(zm, m));
  float e = act ? expf(z - zm) : 0.f;
  float se = e;
#pragma unroll
  for (int m = 32; m; m >>= 1) se += __shfl_xor(se, m);
  if (act) TH[base] = e / se;
  float kt = 0.f;
  if (act) {
    float var = expf(lv);
    kt = var * (1.f / 0.98f) + mu * mu * (1.f / 0.98f) + logf(0.98f) - lv;
  }
  float sk = kt;
#pragma unroll
  for (int m = 32; m; m >>= 1) sk += __shfl_xor(sk, m);
  if (lane == 0) atomicAdd(accp, 0.5f * (sk - (float)K_N));
}

// ---------------------------------------------------------------------------
// decode: BN-apply + row softmax + rec; one block/row (DEC bf16)
// ---------------------------------------------------------------------------
__global__ __launch_bounds__(256) void decode_rec_kern(
    const unsigned short* __restrict__ DECb, const float* __restrict__ mean,
    const float* __restrict__ rstd, const float* __restrict__ bias,
    const float* __restrict__ X, float* __restrict__ accp) {
  __shared__ float sred[256];
  const int row = (int)blockIdx.x, tid = threadIdx.x;
  const size_t base = (size_t)row * V_N;
  float mx = -1e30f;
  for (int j = tid; j < V_N; j += 256) {
    float y = (bf2f(DECb[base + j]) - mean[j]) * rstd[j] + bias[j];
    mx = fmaxf(mx, y);
  }
  sred[tid] = mx; __syncthreads();
  for (int s = 128; s; s >>= 1) { if (tid < s) sred[tid] = fmaxf(sred[tid], sred[tid + s]); __syncthreads(); }
  mx = sred[0]; __syncthreads();

  float se = 0.f;
  for (int j = tid; j < V_N; j += 256) {
    float y = (bf2f(DECb[base + j]) - mean[j]) * rstd[j] + bias[j];
    se += expf(y - mx);
  }
  sred[tid] = se; __syncthreads();
  for (int s = 128; s; s >>= 1) { if (tid < s) sred[tid] += sred[tid + s]; __syncthreads(); }
  se = sred[0]; __syncthreads();

  float part = 0.f;
  for (int j = tid; j < V_N; j += 256) {
    float y = (bf2f(DECb[base + j]) - mean[j]) * rstd[j] + bias[j];
    float p = expf(y - mx) / se;
    part += X[base + j] * logf(p + 1e-10f);
  }
  sred[tid] = part; __syncthreads();
  for (int s = 128; s; s >>= 1) { if (tid < s) sred[tid] += sred[tid + s]; __syncthreads(); }
  if (tid == 0) atomicAdd(accp, -sred[0]);
}

// ---------------------------------------------------------------------------
// Row L2-normalize (BWE -> na/nb)
// ---------------------------------------------------------------------------
__global__ void rownorm_kern(const float* __restrict__ Xp, float* __restrict__ Yp) {
  __shared__ float sred[256];
  const int row = (int)blockIdx.x, tid = threadIdx.x;
  float s = 0.f;
  for (int j = tid; j < E_N; j += 256) { float v = Xp[(size_t)row * E_N + j]; s += v * v; }
  sred[tid] = s; __syncthreads();
  for (int st = 128; st; st >>= 1) { if (tid < st) sred[tid] += sred[tid + st]; __syncthreads(); }
  float sc = 1.f / fmaxf(sqrtf(sred[0]), 1e-12f);
  for (int j = tid; j < E_N; j += 256) Yp[(size_t)row * E_N + j] = Xp[(size_t)row * E_N + j] * sc;
}

// ---------------------------------------------------------------------------
// M = 1 - na @ nb^T ; writes K=exp(-10M), K^T, K*M as bf16 (VP-strided)
// ---------------------------------------------------------------------------
__global__ __launch_bounds__(256) void gemm_nt_cost_kern(
    const float* __restrict__ NAp, const float* __restrict__ NBp,
    unsigned short* __restrict__ Kb, unsigned short* __restrict__ KTb,
    unsigned short* __restrict__ KMb) {
  __shared__ float As[16][68];
  __shared__ float Bs[16][68];
  const int tid = threadIdx.x;
  const int tx = tid & 15, ty = tid >> 4;
  const int row0 = (int)blockIdx.y * 64, col0 = (int)blockIdx.x * 64;
  float acc[4][4];
#pragma unroll
  for (int i = 0; i < 4; ++i)
#pragma unroll
    for (int j = 0; j < 4; ++j) acc[i][j] = 0.f;

  for (int e0 = 0; e0 < E_N; e0 += 16) {
#pragma unroll
    for (int i = 0; i < 4; ++i) {
      int id = tid + 256 * i;
      int m = id >> 4, e = id & 15;
      int ge = e0 + e;
      int gr = row0 + m;
      As[e][m] = (gr < V_N && ge < E_N) ? NAp[(size_t)gr * E_N + ge] : 0.f;
      int gc = col0 + m;
      Bs[e][m] = (gc < V_N && ge < E_N) ? NBp[(size_t)gc * E_N + ge] : 0.f;
    }
    __syncthreads();
#pragma unroll
    for (int kk = 0; kk < 16; ++kk) {
      float4 av = *(const float4*)&As[kk][ty * 4];
      float4 bv = *(const float4*)&Bs[kk][tx * 4];
      float aa[4] = {av.x, av.y, av.z, av.w};
      float bb[4] = {bv.x, bv.y, bv.z, bv.w};
#pragma unroll
      for (int i = 0; i < 4; ++i)
#pragma unroll
        for (int j = 0; j < 4; ++j) acc[i][j] = fmaf(aa[i], bb[j], acc[i][j]);
    }
    __syncthreads();
  }
#pragma unroll
  for (int i = 0; i < 4; ++i) {
    int gi = row0 + ty * 4 + i;
    if (gi >= V_N) continue;
#pragma unroll
    for (int j = 0; j < 4; ++j) {
      int gj = col0 + tx * 4 + j;
      if (gj >= V_N) continue;
      float m = 1.f - acc[i][j];
      float kv = expf(-10.f * m);
      Kb[(size_t)gi * VP + gj] = f2bf(kv);
      KTb[(size_t)gj * VP + gi] = f2bf(kv);
      KMb[(size_t)gi * VP + gj] = f2bf(kv * m);
    }
  }
}

// ---------------------------------------------------------------------------
// a/b marginals: softmax over vocab of phi row t (f32, VP-strided)
// ---------------------------------------------------------------------------
__global__ void topic_softmax_kern(const float* __restrict__ phi, float* __restrict__ ATp) {
  __shared__ float sred[256];
  const int t = (int)blockIdx.x, tid = threadIdx.x;
  const size_t base = (size_t)t * V_N;
  float mx = -1e30f;
  for (int i = tid; i < V_N; i += 256) mx = fmaxf(mx, phi[base + i]);
  sred[tid] = mx; __syncthreads();
  for (int s = 128; s; s >>= 1) { if (tid < s) sred[tid] = fmaxf(sred[tid], sred[tid + s]); __syncthreads(); }
  mx = sred[0]; __syncthreads();
  float se = 0.f;
  for (int i = tid; i < V_N; i += 256) se += expf(phi[base + i] - mx);
  sred[tid] = se; __syncthreads();
  for (int s = 128; s; s >>= 1) { if (tid < s) sred[tid] += sred[tid + s]; __syncthreads(); }
  se = sred[0];
  for (int i = tid; i < V_N; i += 256) ATp[(size_t)t * VP + i] = expf(phi[base + i] - mx) / se;
}

__global__ void vinit_kern(unsigned short* __restrict__ VTp) {
  int id = (int)blockIdx.x * 256 + threadIdx.x;
  if (id >= K_N * V_N) return;
  int t = id / V_N, i = id - t * V_N;
  VTp[(size_t)t * VP + i] = f2bf(1.0f / (float)V_N);
}

__global__ void finalize_kern(const float* __restrict__ accp, float* __restrict__ out) {
  if (threadIdx.x == 0)
    out[0] = (accp[0] + accp[1]) * (1.f / (float)B_N) + 0.1f * accp[2];
}

// ---------------------------------------------------------------------------
// Sinkhorn: 32 WGs x 512 thr, 64 vocab-rows/WG, 8-way k-split (256 cols/wave).
// B-frags (u/v) batch-prefetched via coherent 8B atomics (16 back-to-back per
// topic-tile -> deep ILP); A (K-rows) plain loads, L2-hot (2 MB/XCD).
// Cross-wave k-reduction via 8 disjoint LDS partial buffers (pad-68 stride).
// Fence-free flag barrier (32 arrivals); __syncthreads drains vmcnt before
// the flag store (validated rounds 2-4, absmax 0).
// ---------------------------------------------------------------------------
__device__ __forceinline__ void gbar(int* flags, int epoch, int wg, int tid) {
  __syncthreads();
  if (tid == 0)
    __hip_atomic_store(&flags[wg * 32], epoch, __ATOMIC_RELAXED, __HIP_MEMORY_SCOPE_AGENT);
  if (tid < SK_NWG) {
    int* line = &flags[tid * 32];
    int spin = 0;
    while (__hip_atomic_load(line, __ATOMIC_RELAXED, __HIP_MEMORY_SCOPE_AGENT) < epoch) {
      __builtin_amdgcn_s_sleep(1);
      if (++spin >= (1 << 17)) break;  // bounded: desync -> wrong answer, not hang
    }
  }
  __syncthreads();
}

// MFMA sweep: partials for this wave's 256-col k-slice over 64 rows x 64 topics
__device__ __forceinline__ void sk_mm(
    const unsigned short* __restrict__ Mat, const unsigned short* __restrict__ Xt,
    float* __restrict__ redw, int wg, int w, int lane) {
  const int n = lane & 15, q = lane >> 4;
  const int colb = w * 256 + q * 8;
  const unsigned short* abase = Mat + (size_t)(wg * 64 + n) * VP + colb;
  const unsigned short* bbase = Xt + (size_t)n * VP + colb;
#pragma unroll
  for (int tc = 0; tc < 4; ++tc) {
    bf16x8 Bf[8];
#pragma unroll
    for (int ks = 0; ks < 8; ++ks)                 // 16 independent atomics, no stalls between
      Bf[ks] = coh_load8(bbase + (size_t)tc * (16 * VP) + ks * 32);
    f32x4n acc[4];
#pragma unroll
    for (int m = 0; m < 4; ++m) acc[m] = (f32x4n){0.f, 0.f, 0.f, 0.f};
#pragma unroll
    for (int ks = 0; ks < 8; ++ks) {
#pragma unroll
      for (int m = 0; m < 4; ++m) {
        bf16x8 af = *(const bf16x8*)(abase + (size_t)m * (16 * VP) + ks * 32);
        acc[m] = __builtin_amdgcn_mfma_f32_16x16x32_bf16(af, Bf[ks], acc[m], 0, 0, 0);
      }
    }
#pragma unroll
    for (int m = 0; m < 4; ++m)
#pragma unroll
      for (int r = 0; r < 4; ++r)
        redw[(m * 16 + q * 4 + r) * RED_STRIDE + tc * 16 + n] = acc[m][r];
  }
}

__device__ __forceinline__ void sk_phase(
    const unsigned short* __restrict__ Mat, const unsigned short* __restrict__ Xt,
    const float* __restrict__ Ap, unsigned short* __restrict__ Outp,
    float* red, unsigned short* u_s, int wg, int tid) {
  const int lane = tid & 63, w = tid >> 6;
  sk_mm(Mat, Xt, red + w * RED_WAVE, wg, w, lane);
  __syncthreads();
  {
    const int row = tid >> 3, t0 = (tid & 7) * 8;
    f32x4n s0 = (f32x4n){0.f,0.f,0.f,0.f}, s1 = (f32x4n){0.f,0.f,0.f,0.f};
#pragma unroll
    for (int p = 0; p < 8; ++p) {
      s0 += *(const f32x4n*)&red[p * RED_WAVE + row * RED_STRIDE + t0];
      s1 += *(const f32x4n*)&red[p * RED_WAVE + row * RED_STRIDE + t0 + 4];
    }
    const float* ap = Ap + (size_t)t0 * VP + wg * 64 + row;
#pragma unroll
    for (int i = 0; i < 4; ++i) {
      float u0 = ap[(size_t)i * VP] / (s0[i] + 1e-16f);
      float u1 = ap[(size_t)(i + 4) * VP] / (s1[i] + 1e-16f);
      u_s[row * RED_STRIDE + t0 + i] = f2bf(u0);
      u_s[row * RED_STRIDE + t0 + i + 4] = f2bf(u1);
    }
  }
  __syncthreads();
  {
    const int topic = tid >> 3, r0 = (tid & 7) * 8;
    ushort4 a, b;
    a.x = u_s[(r0 + 0) * RED_STRIDE + topic]; a.y = u_s[(r0 + 1) * RED_STRIDE + topic];
    a.z = u_s[(r0 + 2) * RED_STRIDE + topic]; a.w = u_s[(r0 + 3) * RED_STRIDE + topic];
    b.x = u_s[(r0 + 4) * RED_STRIDE + topic]; b.y = u_s[(r0 + 5) * RED_STRIDE + topic];
    b.z = u_s[(r0 + 6) * RED_STRIDE + topic]; b.w = u_s[(r0 + 7) * RED_STRIDE + topic];
    unsigned short* op = Outp + (size_t)topic * VP + wg * 64 + r0;
    coh_store8(op, a);
    coh_store8(op + 4, b);
  }
}

__global__ void __launch_bounds__(SK_BLK, 1) sinkhorn_kern(
    const unsigned short* __restrict__ Kb, const unsigned short* __restrict__ KTb,
    const unsigned short* __restrict__ KMb, const float* __restrict__ ATp,
    const float* __restrict__ BTp, unsigned short* __restrict__ VTp,
    unsigned short* __restrict__ UTp, float* __restrict__ accp, int* __restrict__ flags) {
  extern __shared__ char smem[];
  float* red = (float*)smem;
  unsigned short* u_s = (unsigned short*)(smem + 8 * RED_WAVE * 4);
  const int wg = (int)blockIdx.x, tid = threadIdx.x;
  const int lane = tid & 63, w = tid >> 6;

  for (int it = 0; it < SK_ITER; ++it) {
    sk_phase(Kb, VTp, ATp, UTp, red, u_s, wg, tid);
    gbar(flags, 2 * it + 1, wg, tid);
    sk_phase(KTb, UTp, BTp, VTp, red, u_s, wg, tid);
    gbar(flags, 2 * it + 2, wg, tid);
  }

  // final: u = a/(K v + eps); s_loss = sum u * ((K*M) v)
  const int row = tid >> 3, t0 = (tid & 7) * 8;
  float uloc[8];

  sk_mm(Kb, VTp, red + w * RED_WAVE, wg, w, lane);
  __syncthreads();
  {
    f32x4n s0 = (f32x4n){0.f,0.f,0.f,0.f}, s1 = (f32x4n){0.f,0.f,0.f,0.f};
#pragma unroll
    for (int p = 0; p < 8; ++p) {
      s0 += *(const f32x4n*)&red[p * RED_WAVE + row * RED_STRIDE + t0];
      s1 += *(const f32x4n*)&red[p * RED_WAVE + row * RED_STRIDE + t0 + 4];
    }
    const float* ap = ATp + (size_t)t0 * VP + wg * 64 + row;
#pragma unroll
    for (int i = 0; i < 4; ++i) {
      uloc[i]     = ap[(size_t)i * VP]       / (s0[i] + 1e-16f);
      uloc[i + 4] = ap[(size_t)(i + 4) * VP] / (s1[i] + 1e-16f);
    }
  }
  __syncthreads();
  sk_mm(KMb, VTp, red + w * RED_WAVE, wg, w, lane);
  __syncthreads();
  float part = 0.f;
  {
    f32x4n s0 = (f32x4n){0.f,0.f,0.f,0.f}, s1 = (f32x4n){0.f,0.f,0.f,0.f};
#pragma unroll
    for (int p = 0; p < 8; ++p) {
      s0 += *(const f32x4n*)&red[p * RED_WAVE + row * RED_STRIDE + t0];
      s1 += *(const f32x4n*)&red[p * RED_WAVE + row * RED_STRIDE + t0 + 4];
    }
#pragma unroll
    for (int i = 0; i < 4; ++i) part += uloc[i] * s0[i] + uloc[i + 4] * s1[i];
  }
  __syncthreads();
  red[tid] = part; __syncthreads();
  for (int st = 256; st; st >>= 1) { if (tid < st) red[tid] += red[tid + st]; __syncthreads(); }
  if (tid == 0) atomicAdd(accp + 2, red[0]);
}

// ---------------------------------------------------------------------------
extern "C" void kernel_launch(void* const* d_in, const int* in_sizes, int n_in,
                              void* d_out, int out_size, void* d_ws, size_t ws_size,
                              hipStream_t stream) {
  const float* x_a   = (const float*)d_in[0];
  const float* x_b   = (const float*)d_in[1];
  const float* eps_a = (const float*)d_in[2];
  const float* eps_b = (const float*)d_in[3];
  const float* W1_a  = (const float*)d_in[4];
  const float* b1_a  = (const float*)d_in[5];
  const float* W2_a  = (const float*)d_in[6];
  const float* b2_a  = (const float*)d_in[7];
  const float* Wmu_a = (const float*)d_in[8];
  const float* bmu_a = (const float*)d_in[9];
  const float* Wlv_a = (const float*)d_in[10];
  const float* blv_a = (const float*)d_in[11];
  const float* mbn_a = (const float*)d_in[12];
  const float* lbn_a = (const float*)d_in[13];
  const float* W1_b  = (const float*)d_in[14];
  const float* b1_b  = (const float*)d_in[15];
  const float* W2_b  = (const float*)d_in[16];
  const float* b2_b  = (const float*)d_in[17];
  const float* Wmu_b = (const float*)d_in[18];
  const float* bmu_b = (const float*)d_in[19];
  const float* Wlv_b = (const float*)d_in[20];
  const float* blv_b = (const float*)d_in[21];
  const float* mbn_b = (const float*)d_in[22];
  const float* lbn_b = (const float*)d_in[23];
  const float* dbn_a = (const float*)d_in[24];
  const float* dbn_b = (const float*)d_in[25];
  const float* phi_a = (const float*)d_in[26];
  const float* phi_b = (const float*)d_in[27];
  const float* bwe_a = (const float*)d_in[28];
  const float* bwe_b = (const float*)d_in[29];
  float* out = (float*)d_out;

  // ---- static workspace layout with phase aliasing (~35.3 MB total) ----
  char* ws = (char*)d_ws;
  const size_t OFF_ACC  = 0;                    // 256 B
  const size_t OFF_BAR  = 256;                  // flags: 32 lines x 128 B (16 KB reserved)
  const size_t OFF_ST   = OFF_BAR + 16384;
  const size_t OFF_TH   = OFF_ST + 49152;
  const size_t OFF_MU   = OFF_TH + 819200;
  const size_t OFF_LV   = OFF_MU + 819200;
  const size_t OFF_BIG  = OFF_LV + 819200;
  // phase-1 overlay of BIG
  const size_t OFF_H1   = OFF_BIG;              // 8,192,000
  const size_t OFF_H2   = OFF_H1 + 8192000;     // 8,192,000
  const size_t OFF_DEC  = OFF_H2 + 8192000;     // 16,384,000 (bf16)
  // phase-2 overlay of BIG
  const size_t OFF_NA   = OFF_BIG;
  const size_t OFF_NB   = OFF_NA + 2400000;
  const size_t OFF_KB   = OFF_NB + 2400000;
  const size_t OFF_KT   = OFF_KB + 8388608;
  const size_t OFF_KM   = OFF_KT + 8388608;
  const size_t OFF_AT   = OFF_KM + 8388608;
  const size_t OFF_BT   = OFF_AT + 524288;
  const size_t OFF_VT   = OFF_BT + 524288;
  const size_t OFF_UT   = OFF_VT + 262144;
  const size_t NEED     = OFF_DEC + 16384000;   // ~35.3 MB
  if (ws_size < NEED) return;

  float* ACCp = (float*)(ws + OFF_ACC);
  int*   FLGp = (int*)(ws + OFF_BAR);
  float* STp  = (float*)(ws + OFF_ST);
  float* st_sum = STp, *st_sq = STp + 2048;
  float* mmean = STp + 4096, *mrstd = STp + 6144;
  float* lmean = STp + 8192, *lrstd = STp + 10240;
  float* THp  = (float*)(ws + OFF_TH);
  float* MUp  = (float*)(ws + OFF_MU);
  float* LVp  = (float*)(ws + OFF_LV);
  float* H1p  = (float*)(ws + OFF_H1);
  float* H2p  = (float*)(ws + OFF_H2);
  unsigned short* DECb = (unsigned short*)(ws + OFF_DEC);
  float* NAp  = (float*)(ws + OFF_NA);
  float* NBp  = (float*)(ws + OFF_NB);
  unsigned short* KBp = (unsigned short*)(ws + OFF_KB);
  unsigned short* KTp = (unsigned short*)(ws + OFF_KT);
  unsigned short* KMp = (unsigned short*)(ws + OFF_KM);
  float* ATp  = (float*)(ws + OFF_AT);
  float* BTp  = (float*)(ws + OFF_BT);
  unsigned short* VTp = (unsigned short*)(ws + OFF_VT);
  unsigned short* UTp = (unsigned short*)(ws + OFF_UT);

  hipMemsetAsync(ACCp, 0, 256, stream);
  hipMemsetAsync(FLGp, 0, 16384, stream);

  auto enc_dec = [&](const float* x, const float* eps, const float* W1, const float* b1,
                     const float* W2, const float* b2, const float* Wmu, const float* bmu,
                     const float* Wlv, const float* blv, const float* mbn, const float* lbn,
                     const float* phi, const float* dbn, float* accp) {
    gemm_nn_kern<<<dim3(8, 64), 256, 0, stream>>>(x, W1, b1, H1p, B_N, H_N, V_N, 1, 0);
    gemm_nn_kern<<<dim3(8, 64), 256, 0, stream>>>(H1p, W2, b2, H2p, B_N, H_N, H_N, 1, 0);
    gemm_nn_kern<<<dim3(1, 64), 256, 0, stream>>>(H2p, Wmu, bmu, MUp, B_N, K_N, H_N, 0, 0);
    gemm_nn_kern<<<dim3(1, 64), 256, 0, stream>>>(H2p, Wlv, blv, LVp, B_N, K_N, H_N, 0, 0);
    hipMemsetAsync(st_sum, 0, 2 * 2048 * 4, stream);
    colstats2_kern<<<dim3(1, 16), 256, 0, stream>>>(MUp, K_N, 256, st_sum, st_sq);
    finstats_kern<<<1, 256, 0, stream>>>(st_sum, st_sq, K_N, 1.f / B_N, mmean, mrstd);
    hipMemsetAsync(st_sum, 0, 2 * 2048 * 4, stream);
    colstats2_kern<<<dim3(1, 16), 256, 0, stream>>>(LVp, K_N, 256, st_sum, st_sq);
    finstats_kern<<<1, 256, 0, stream>>>(st_sum, st_sq, K_N, 1.f / B_N, lmean, lrstd);
    reparam_kern<<<B_N / 4, 256, 0, stream>>>(MUp, LVp, mmean, mrstd, lmean, lrstd,
                                              mbn, lbn, eps, THp, accp);
    gemm_nn_kern<<<dim3(32, 64), 256, 0, stream>>>(THp, phi, nullptr, DECb, B_N, V_N, K_N, 0, 1);
    hipMemsetAsync(st_sum, 0, 2 * 2048 * 4, stream);
    colstats2_bf_kern<<<dim3(8, 16), 256, 0, stream>>>(DECb, V_N, 256, st_sum, st_sq);
    finstats_kern<<<8, 256, 0, stream>>>(st_sum, st_sq, V_N, 1.f / B_N, mmean, mrstd);
    decode_rec_kern<<<B_N, 256, 0, stream>>>(DECb, mmean, mrstd, dbn, x, accp);
  };

  enc_dec(x_a, eps_a, W1_a, b1_a, W2_a, b2_a, Wmu_a, bmu_a, Wlv_a, blv_a, mbn_a, lbn_a,
          phi_a, dbn_a, ACCp + 0);
  enc_dec(x_b, eps_b, W1_b, b1_b, W2_b, b2_b, Wmu_b, bmu_b, Wlv_b, blv_b, mbn_b, lbn_b,
          phi_b, dbn_b, ACCp + 1);

  // ---- phase 2: Sinkhorn prep (aliases the H1/H2/DEC region; stream-ordered) ----
  hipMemsetAsync(KBp, 0, (size_t)VP * VP * 2, stream);
  hipMemsetAsync(KTp, 0, (size_t)VP * VP * 2, stream);
  hipMemsetAsync(KMp, 0, (size_t)VP * VP * 2, stream);
  hipMemsetAsync(ATp, 0, (size_t)TP * VP * 4, stream);
  hipMemsetAsync(BTp, 0, (size_t)TP * VP * 4, stream);
  hipMemsetAsync(VTp, 0, (size_t)TP * VP * 2, stream);
  hipMemsetAsync(UTp, 0, (size_t)TP * VP * 2, stream);

  rownorm_kern<<<V_N, 256, 0, stream>>>(bwe_a, NAp);
  rownorm_kern<<<V_N, 256, 0, stream>>>(bwe_b, NBp);
  gemm_nt_cost_kern<<<dim3(32, 32), 256, 0, stream>>>(NAp, NBp, KBp, KTp, KMp);
  topic_softmax_kern<<<K_N, 256, 0, stream>>>(phi_a, ATp);
  topic_softmax_kern<<<K_N, 256, 0, stream>>>(phi_b, BTp);
  vinit_kern<<<(K_N * V_N + 255) / 256, 256, 0, stream>>>(VTp);

  // ---- Sinkhorn main loop: 32 WGs x 512 thr, 148 KB dynamic LDS ----
  hipFuncSetAttribute((const void*)sinkhorn_kern,
                      hipFuncAttributeMaxDynamicSharedMemorySize, SK_LDS);
  sinkhorn_kern<<<dim3(SK_NWG), dim3(SK_BLK), SK_LDS, stream>>>(
      KBp, KTp, KMp, ATp, BTp, VTp, UTp, ACCp, FLGp);

  finalize_kern<<<1, 64, 0, stream>>>(ACCp, out);
  (void)in_sizes; (void)n_in; (void)out_size;
}

// Round 6
// 22011.746 us; speedup vs baseline: 1.4866x; 1.4866x over previous
//
#include <hip/hip_runtime.h>

// Problem dims
#define B_N 4096
#define V_N 2000
#define K_N 50
#define H_N 500
#define E_N 300
#define VP  2048   // padded vocab (mult of 32 for MFMA k)
#define TP  64     // padded topics
#define SK_NWG 128
#define SK_ITER 500

typedef short bf16x8 __attribute__((ext_vector_type(8)));
typedef float f32x4n __attribute__((ext_vector_type(4)));

__device__ __forceinline__ unsigned short f2bf(float f) {
  unsigned int x = __float_as_uint(f);
  x = (x + 0x7FFFu + ((x >> 16) & 1u)) >> 16;
  return (unsigned short)x;
}
__device__ __forceinline__ float bf2f(unsigned short h) {
  return __uint_as_float((unsigned int)h << 16);
}
__device__ __forceinline__ float softplusf(float x) {
  return fmaxf(x, 0.f) + log1pf(expf(-fabsf(x)));
}

// Agent-coherent 16B load as two 8B relaxed atomics (bypass non-coherent L2,
// serviced at the coherence point). Used ONLY for u/v.
__device__ __forceinline__ bf16x8 coh_load8(const unsigned short* p) {
  unsigned long long lo = __hip_atomic_load((const unsigned long long*)p,
                                            __ATOMIC_RELAXED, __HIP_MEMORY_SCOPE_AGENT);
  unsigned long long hi = __hip_atomic_load((const unsigned long long*)(p + 4),
                                            __ATOMIC_RELAXED, __HIP_MEMORY_SCOPE_AGENT);
  union { unsigned long long u[2]; bf16x8 v; } cvt;
  cvt.u[0] = lo; cvt.u[1] = hi;
  return cvt.v;
}
__device__ __forceinline__ void coh_store8(unsigned short* p, ushort4 val) {
  union { ushort4 s; unsigned long long u; } cvt; cvt.s = val;
  __hip_atomic_store((unsigned long long*)p, cvt.u,
                     __ATOMIC_RELAXED, __HIP_MEMORY_SCOPE_AGENT);
}

// ---------------------------------------------------------------------------
// fp32 tiled GEMM: C = act(A(MxK) @ B(KxN) + bias); act: 0 none, 1 softplus
// ---------------------------------------------------------------------------
__global__ __launch_bounds__(256) void gemm_nn_kern(
    const float* __restrict__ A, const float* __restrict__ Bm,
    const float* __restrict__ bias, void* __restrict__ Cv,
    int M, int N, int Kd, int act, int bf16out) {
  __shared__ float As[16][68];
  __shared__ float Bs[16][68];
  const int tid = threadIdx.x;
  const int tx = tid & 15, ty = tid >> 4;
  const int row0 = (int)blockIdx.y * 64, col0 = (int)blockIdx.x * 64;
  float acc[4][4];
#pragma unroll
  for (int i = 0; i < 4; ++i)
#pragma unroll
    for (int j = 0; j < 4; ++j) acc[i][j] = 0.f;

  for (int k0 = 0; k0 < Kd; k0 += 16) {
#pragma unroll
    for (int i = 0; i < 4; ++i) {
      int id = tid + 256 * i;
      int m = id >> 4, kk = id & 15;
      int gr = row0 + m, gk = k0 + kk;
      As[kk][m] = (gr < M && gk < Kd) ? A[(size_t)gr * Kd + gk] : 0.f;
    }
#pragma unroll
    for (int i = 0; i < 4; ++i) {
      int id = tid + 256 * i;
      int kk = id >> 6, n = id & 63;
      int gk = k0 + kk, gc = col0 + n;
      Bs[kk][n] = (gk < Kd && gc < N) ? Bm[(size_t)gk * N + gc] : 0.f;
    }
    __syncthreads();
#pragma unroll
    for (int kk = 0; kk < 16; ++kk) {
      float4 av = *(const float4*)&As[kk][ty * 4];
      float4 bv = *(const float4*)&Bs[kk][tx * 4];
      float aa[4] = {av.x, av.y, av.z, av.w};
      float bb[4] = {bv.x, bv.y, bv.z, bv.w};
#pragma unroll
      for (int i = 0; i < 4; ++i)
#pragma unroll
        for (int j = 0; j < 4; ++j) acc[i][j] = fmaf(aa[i], bb[j], acc[i][j]);
    }
    __syncthreads();
  }
#pragma unroll
  for (int i = 0; i < 4; ++i) {
    int row = row0 + ty * 4 + i;
    if (row >= M) continue;
#pragma unroll
    for (int j = 0; j < 4; ++j) {
      int col = col0 + tx * 4 + j;
      if (col >= N) continue;
      float v = acc[i][j] + (bias ? bias[col] : 0.f);
      if (act) v = softplusf(v);
      if (bf16out) ((unsigned short*)Cv)[(size_t)row * N + col] = f2bf(v);
      else         ((float*)Cv)[(size_t)row * N + col] = v;
    }
  }
}

// ---------------------------------------------------------------------------
// Column partial sums (BN stats)
// ---------------------------------------------------------------------------
__global__ void colstats2_kern(const float* __restrict__ X, int C, int rowsPer,
                               float* __restrict__ sums, float* __restrict__ sumsq) {
  int c = (int)blockIdx.x * 256 + threadIdx.x;
  if (c >= C) return;
  int r0 = (int)blockIdx.y * rowsPer;
  float s = 0.f, s2 = 0.f;
  for (int r = r0; r < r0 + rowsPer; ++r) {
    float v = X[(size_t)r * C + c];
    s += v; s2 += v * v;
  }
  atomicAdd(&sums[c], s);
  atomicAdd(&sumsq[c], s2);
}

__global__ void colstats2_bf_kern(const unsigned short* __restrict__ X, int C, int rowsPer,
                                  float* __restrict__ sums, float* __restrict__ sumsq) {
  int c = (int)blockIdx.x * 256 + threadIdx.x;
  if (c >= C) return;
  int r0 = (int)blockIdx.y * rowsPer;
  float s = 0.f, s2 = 0.f;
  for (int r = r0; r < r0 + rowsPer; ++r) {
    float v = bf2f(X[(size_t)r * C + c]);
    s += v; s2 += v * v;
  }
  atomicAdd(&sums[c], s);
  atomicAdd(&sumsq[c], s2);
}

__global__ void finstats_kern(const float* __restrict__ sums, const float* __restrict__ sumsq,
                              int C, float invM, float* __restrict__ mean,
                              float* __restrict__ rstd) {
  int c = (int)blockIdx.x * 256 + threadIdx.x;
  if (c >= C) return;
  float mu = sums[c] * invM;
  float var = sumsq[c] * invM - mu * mu;
  mean[c] = mu;
  rstd[c] = rsqrtf(var + 1e-5f);
}

// ---------------------------------------------------------------------------
// BN-apply + reparam + row-softmax(50) -> theta ; accumulate KLD
// ---------------------------------------------------------------------------
__global__ __launch_bounds__(256) void reparam_kern(
    const float* __restrict__ MUp, const float* __restrict__ LVp,
    const float* __restrict__ mmean, const float* __restrict__ mrstd,
    const float* __restrict__ lmean, const float* __restrict__ lrstd,
    const float* __restrict__ mbn, const float* __restrict__ lbn,
    const float* __restrict__ epsb, float* __restrict__ TH,
    float* __restrict__ accp) {
  const int wave = threadIdx.x >> 6, lane = threadIdx.x & 63;
  const int row = (int)blockIdx.x * 4 + wave;
  const bool act = lane < K_N;
  float mu = 0.f, lv = 0.f, z = 0.f;
  size_t base = (size_t)row * K_N + lane;
  if (act) {
    mu = (MUp[base] - mmean[lane]) * mrstd[lane] + mbn[lane];
    lv = (LVp[base] - lmean[lane]) * lrstd[lane] + lbn[lane];
    z = mu + expf(0.5f * lv) * epsb[base];
  }
  float zm = act ? z : -1e30f;
#pragma unroll
  for (int m = 32; m; m >>= 1) zm = fmaxf(zm, __shfl_xor(zm, m));
  float e = act ? expf(z - zm) : 0.f;
  float se = e;
#pragma unroll
  for (int m = 32; m; m >>= 1) se += __shfl_xor(se, m);
  if (act) TH[base] = e / se;
  float kt = 0.f;
  if (act) {
    float var = expf(lv);
    kt = var * (1.f / 0.98f) + mu * mu * (1.f / 0.98f) + logf(0.98f) - lv;
  }
  float sk = kt;
#pragma unroll
  for (int m = 32; m; m >>= 1) sk += __shfl_xor(sk, m);
  if (lane == 0) atomicAdd(accp, 0.5f * (sk - (float)K_N));
}

// ---------------------------------------------------------------------------
// decode: BN-apply + row softmax + rec; one block/row (DEC bf16)
// ---------------------------------------------------------------------------
__global__ __launch_bounds__(256) void decode_rec_kern(
    const unsigned short* __restrict__ DECb, const float* __restrict__ mean,
    const float* __restrict__ rstd, const float* __restrict__ bias,
    const float* __restrict__ X, float* __restrict__ accp) {
  __shared__ float sred[256];
  const int row = (int)blockIdx.x, tid = threadIdx.x;
  const size_t base = (size_t)row * V_N;
  float mx = -1e30f;
  for (int j = tid; j < V_N; j += 256) {
    float y = (bf2f(DECb[base + j]) - mean[j]) * rstd[j] + bias[j];
    mx = fmaxf(mx, y);
  }
  sred[tid] = mx; __syncthreads();
  for (int s = 128; s; s >>= 1) { if (tid < s) sred[tid] = fmaxf(sred[tid], sred[tid + s]); __syncthreads(); }
  mx = sred[0]; __syncthreads();

  float se = 0.f;
  for (int j = tid; j < V_N; j += 256) {
    float y = (bf2f(DECb[base + j]) - mean[j]) * rstd[j] + bias[j];
    se += expf(y - mx);
  }
  sred[tid] = se; __syncthreads();
  for (int s = 128; s; s >>= 1) { if (tid < s) sred[tid] += sred[tid + s]; __syncthreads(); }
  se = sred[0]; __syncthreads();

  float part = 0.f;
  for (int j = tid; j < V_N; j += 256) {
    float y = (bf2f(DECb[base + j]) - mean[j]) * rstd[j] + bias[j];
    float p = expf(y - mx) / se;
    part += X[base + j] * logf(p + 1e-10f);
  }
  sred[tid] = part; __syncthreads();
  for (int s = 128; s; s >>= 1) { if (tid < s) sred[tid] += sred[tid + s]; __syncthreads(); }
  if (tid == 0) atomicAdd(accp, -sred[0]);
}

// ---------------------------------------------------------------------------
// Row L2-normalize (BWE -> na/nb)
// ---------------------------------------------------------------------------
__global__ void rownorm_kern(const float* __restrict__ Xp, float* __restrict__ Yp) {
  __shared__ float sred[256];
  const int row = (int)blockIdx.x, tid = threadIdx.x;
  float s = 0.f;
  for (int j = tid; j < E_N; j += 256) { float v = Xp[(size_t)row * E_N + j]; s += v * v; }
  sred[tid] = s; __syncthreads();
  for (int st = 128; st; st >>= 1) { if (tid < st) sred[tid] += sred[tid + st]; __syncthreads(); }
  float sc = 1.f / fmaxf(sqrtf(sred[0]), 1e-12f);
  for (int j = tid; j < E_N; j += 256) Yp[(size_t)row * E_N + j] = Xp[(size_t)row * E_N + j] * sc;
}

// ---------------------------------------------------------------------------
// M = 1 - na @ nb^T ; writes K=exp(-10M), K^T, K*M as bf16 (VP-strided)
// ---------------------------------------------------------------------------
__global__ __launch_bounds__(256) void gemm_nt_cost_kern(
    const float* __restrict__ NAp, const float* __restrict__ NBp,
    unsigned short* __restrict__ Kb, unsigned short* __restrict__ KTb,
    unsigned short* __restrict__ KMb) {
  __shared__ float As[16][68];
  __shared__ float Bs[16][68];
  const int tid = threadIdx.x;
  const int tx = tid & 15, ty = tid >> 4;
  const int row0 = (int)blockIdx.y * 64, col0 = (int)blockIdx.x * 64;
  float acc[4][4];
#pragma unroll
  for (int i = 0; i < 4; ++i)
#pragma unroll
    for (int j = 0; j < 4; ++j) acc[i][j] = 0.f;

  for (int e0 = 0; e0 < E_N; e0 += 16) {
#pragma unroll
    for (int i = 0; i < 4; ++i) {
      int id = tid + 256 * i;
      int m = id >> 4, e = id & 15;
      int ge = e0 + e;
      int gr = row0 + m;
      As[e][m] = (gr < V_N && ge < E_N) ? NAp[(size_t)gr * E_N + ge] : 0.f;
      int gc = col0 + m;
      Bs[e][m] = (gc < V_N && ge < E_N) ? NBp[(size_t)gc * E_N + ge] : 0.f;
    }
    __syncthreads();
#pragma unroll
    for (int kk = 0; kk < 16; ++kk) {
      float4 av = *(const float4*)&As[kk][ty * 4];
      float4 bv = *(const float4*)&Bs[kk][tx * 4];
      float aa[4] = {av.x, av.y, av.z, av.w};
      float bb[4] = {bv.x, bv.y, bv.z, bv.w};
#pragma unroll
      for (int i = 0; i < 4; ++i)
#pragma unroll
        for (int j = 0; j < 4; ++j) acc[i][j] = fmaf(aa[i], bb[j], acc[i][j]);
    }
    __syncthreads();
  }
#pragma unroll
  for (int i = 0; i < 4; ++i) {
    int gi = row0 + ty * 4 + i;
    if (gi >= V_N) continue;
#pragma unroll
    for (int j = 0; j < 4; ++j) {
      int gj = col0 + tx * 4 + j;
      if (gj >= V_N) continue;
      float m = 1.f - acc[i][j];
      float kv = expf(-10.f * m);
      Kb[(size_t)gi * VP + gj] = f2bf(kv);
      KTb[(size_t)gj * VP + gi] = f2bf(kv);
      KMb[(size_t)gi * VP + gj] = f2bf(kv * m);
    }
  }
}

// ---------------------------------------------------------------------------
// a/b marginals: softmax over vocab of phi row t (f32, VP-strided)
// ---------------------------------------------------------------------------
__global__ void topic_softmax_kern(const float* __restrict__ phi, float* __restrict__ ATp) {
  __shared__ float sred[256];
  const int t = (int)blockIdx.x, tid = threadIdx.x;
  const size_t base = (size_t)t * V_N;
  float mx = -1e30f;
  for (int i = tid; i < V_N; i += 256) mx = fmaxf(mx, phi[base + i]);
  sred[tid] = mx; __syncthreads();
  for (int s = 128; s; s >>= 1) { if (tid < s) sred[tid] = fmaxf(sred[tid], sred[tid + s]); __syncthreads(); }
  mx = sred[0]; __syncthreads();
  float se = 0.f;
  for (int i = tid; i < V_N; i += 256) se += expf(phi[base + i] - mx);
  sred[tid] = se; __syncthreads();
  for (int s = 128; s; s >>= 1) { if (tid < s) sred[tid] += sred[tid + s]; __syncthreads(); }
  se = sred[0];
  for (int i = tid; i < V_N; i += 256) ATp[(size_t)t * VP + i] = expf(phi[base + i] - mx) / se;
}

__global__ void vinit_kern(unsigned short* __restrict__ VTp) {
  int id = (int)blockIdx.x * 256 + threadIdx.x;
  if (id >= K_N * V_N) return;
  int t = id / V_N, i = id - t * V_N;
  VTp[(size_t)t * VP + i] = f2bf(1.0f / (float)V_N);
}

__global__ void finalize_kern(const float* __restrict__ accp, float* __restrict__ out) {
  if (threadIdx.x == 0)
    out[0] = (accp[0] + accp[1]) * (1.f / (float)B_N) + 0.1f * accp[2];
}

// ---------------------------------------------------------------------------
// Sinkhorn: 500 iters of u=a/(Kv), v=b/(K^T u), then transport cost.
// R4 topology (128 WGs x 256 thr, 16 rows/WG, 4-wave x 512-col k-split) with
// a DEEP-PIPELINED coherent-load inner loop:
//   - all 16 A-fragments hoisted to registers (t-invariant; fixes R5's 4x bug)
//   - B (v) fragments double-buffered in batches of 16 (256 B/lane in flight;
//     ~16 KB/wave, ~64 KB/CU) so the IF round-trip is throughput- not
//     latency-bound. Fence-free flag barrier (validated R4, absmax 0).
// ---------------------------------------------------------------------------
__device__ __forceinline__ void gbar(int* flags, int epoch, int wg, int tid) {
  __syncthreads();  // all waves arrived; per-wave vmcnt(0) drained (coh stores at IF)
  if (tid == 0)
    __hip_atomic_store(&flags[wg * 32], epoch, __ATOMIC_RELAXED, __HIP_MEMORY_SCOPE_AGENT);
  {
    int* line = &flags[(tid & (SK_NWG - 1)) * 32];
    int spin = 0;
    while (__hip_atomic_load(line, __ATOMIC_RELAXED, __HIP_MEMORY_SCOPE_AGENT) < epoch) {
      __builtin_amdgcn_s_sleep(1);
      if (++spin >= (1 << 17)) break;  // bounded: desync -> wrong answer, not hang
    }
  }
  __syncthreads();
}

// MFMA sweep with pipelined loads: writes this wave's 4 topic-tile partials
// (16 rows x 64 topics for its 512-col k-slice) into red[wave].
__device__ __forceinline__ void sk_mm16(
    const unsigned short* __restrict__ Mat, const unsigned short* __restrict__ Xt,
    float* __restrict__ red, int wg, int wave, int lane) {
  const int m = lane & 15, q = lane >> 4;
  const unsigned short* arow = Mat + (size_t)(wg * 16 + m) * VP + wave * 512 + q * 8;
  const unsigned short* xrow = Xt + (size_t)m * VP + wave * 512 + q * 8;
  bf16x8 Af[16];
#pragma unroll
  for (int ks = 0; ks < 16; ++ks) Af[ks] = *(const bf16x8*)(arow + ks * 32);  // K: L2-hot
  bf16x8 B0[16], B1[16];
#pragma unroll
  for (int ks = 0; ks < 16; ++ks) B0[ks] = coh_load8(xrow + ks * 32);         // v batch 0
#pragma unroll
  for (int t = 0; t < 4; ++t) {
    const bf16x8* cur = (t & 1) ? B1 : B0;
    bf16x8* nxt = (t & 1) ? B0 : B1;
    if (t < 3) {
#pragma unroll
      for (int ks = 0; ks < 16; ++ks)       // prefetch next batch; overlaps MFMAs below
        nxt[ks] = coh_load8(xrow + (size_t)(t + 1) * (16 * VP) + ks * 32);
    }
    f32x4n a = (f32x4n){0.f, 0.f, 0.f, 0.f};
#pragma unroll
    for (int ks = 0; ks < 16; ++ks)
      a = __builtin_amdgcn_mfma_f32_16x16x32_bf16(Af[ks], cur[ks], a, 0, 0, 0);
    *(f32x4n*)&red[wave * 1280 + (t * 16 + m) * 20 + q * 4] = a;
  }
}

__device__ __forceinline__ void sk_phase(
    const unsigned short* __restrict__ Mat, const unsigned short* __restrict__ Xt,
    const float* __restrict__ Ap, unsigned short* __restrict__ Outp,
    float* red, int wg, int wave, int lane, int tid) {
  sk_mm16(Mat, Xt, red, wg, wave, lane);
  __syncthreads();
  {
    const int c = tid >> 2, r0 = (tid & 3) * 4;   // c: topic 0..63, r0: row-group
    f32x4n s = (f32x4n){0.f, 0.f, 0.f, 0.f};
#pragma unroll
    for (int w = 0; w < 4; ++w) s += *(const f32x4n*)&red[w * 1280 + c * 20 + r0];
    f32x4n a4 = *(const f32x4n*)(Ap + (size_t)c * VP + wg * 16 + r0);
    f32x4n u = a4 / (s + 1e-16f);
    ushort4 ub;
    ub.x = f2bf(u.x); ub.y = f2bf(u.y); ub.z = f2bf(u.z); ub.w = f2bf(u.w);
    coh_store8(Outp + (size_t)c * VP + wg * 16 + r0, ub);
  }
  __syncthreads();
}

__global__ void __launch_bounds__(256, 1) sinkhorn_kern(
    const unsigned short* __restrict__ Kb, const unsigned short* __restrict__ KTb,
    const unsigned short* __restrict__ KMb, const float* __restrict__ ATp,
    const float* __restrict__ BTp, unsigned short* __restrict__ VTp,
    unsigned short* __restrict__ UTp, float* __restrict__ accp, int* __restrict__ flags) {
  __shared__ float red[5120];
  const int wg = (int)blockIdx.x, tid = threadIdx.x;
  const int wave = tid >> 6, lane = tid & 63;

  for (int it = 0; it < SK_ITER; ++it) {
    sk_phase(Kb, VTp, ATp, UTp, red, wg, wave, lane, tid);
    gbar(flags, 2 * it + 1, wg, tid);
    sk_phase(KTb, UTp, BTp, VTp, red, wg, wave, lane, tid);
    gbar(flags, 2 * it + 2, wg, tid);
  }

  // final: u = a/(K v + eps); s_loss = sum u * ((K*M) v)
  const int c = tid >> 2, r0 = (tid & 3) * 4;
  float u4[4];

  sk_mm16(Kb, VTp, red, wg, wave, lane);
  __syncthreads();
  {
    f32x4n s = (f32x4n){0.f, 0.f, 0.f, 0.f};
#pragma unroll
    for (int w = 0; w < 4; ++w) s += *(const f32x4n*)&red[w * 1280 + c * 20 + r0];
    f32x4n a4 = *(const f32x4n*)(ATp + (size_t)c * VP + wg * 16 + r0);
#pragma unroll
    for (int i = 0; i < 4; ++i) u4[i] = a4[i] / (s[i] + 1e-16f);
  }
  __syncthreads();
  sk_mm16(KMb, VTp, red, wg, wave, lane);
  __syncthreads();
  float part = 0.f;
  {
    f32x4n s = (f32x4n){0.f, 0.f, 0.f, 0.f};
#pragma unroll
    for (int w = 0; w < 4; ++w) s += *(const f32x4n*)&red[w * 1280 + c * 20 + r0];
#pragma unroll
    for (int i = 0; i < 4; ++i) part += u4[i] * s[i];
  }
  __syncthreads();
  red[tid] = part; __syncthreads();
  for (int st = 128; st; st >>= 1) { if (tid < st) red[tid] += red[tid + st]; __syncthreads(); }
  if (tid == 0) atomicAdd(accp + 2, red[0]);
}

// ---------------------------------------------------------------------------
extern "C" void kernel_launch(void* const* d_in, const int* in_sizes, int n_in,
                              void* d_out, int out_size, void* d_ws, size_t ws_size,
                              hipStream_t stream) {
  const float* x_a   = (const float*)d_in[0];
  const float* x_b   = (const float*)d_in[1];
  const float* eps_a = (const float*)d_in[2];
  const float* eps_b = (const float*)d_in[3];
  const float* W1_a  = (const float*)d_in[4];
  const float* b1_a  = (const float*)d_in[5];
  const float* W2_a  = (const float*)d_in[6];
  const float* b2_a  = (const float*)d_in[7];
  const float* Wmu_a = (const float*)d_in[8];
  const float* bmu_a = (const float*)d_in[9];
  const float* Wlv_a = (const float*)d_in[10];
  const float* blv_a = (const float*)d_in[11];
  const float* mbn_a = (const float*)d_in[12];
  const float* lbn_a = (const float*)d_in[13];
  const float* W1_b  = (const float*)d_in[14];
  const float* b1_b  = (const float*)d_in[15];
  const float* W2_b  = (const float*)d_in[16];
  const float* b2_b  = (const float*)d_in[17];
  const float* Wmu_b = (const float*)d_in[18];
  const float* bmu_b = (const float*)d_in[19];
  const float* Wlv_b = (const float*)d_in[20];
  const float* blv_b = (const float*)d_in[21];
  const float* mbn_b = (const float*)d_in[22];
  const float* lbn_b = (const float*)d_in[23];
  const float* dbn_a = (const float*)d_in[24];
  const float* dbn_b = (const float*)d_in[25];
  const float* phi_a = (const float*)d_in[26];
  const float* phi_b = (const float*)d_in[27];
  const float* bwe_a = (const float*)d_in[28];
  const float* bwe_b = (const float*)d_in[29];
  float* out = (float*)d_out;

  // ---- static workspace layout with phase aliasing (~35.3 MB total) ----
  char* ws = (char*)d_ws;
  const size_t OFF_ACC  = 0;                    // 256 B
  const size_t OFF_BAR  = 256;                  // flags: 128 lines x 128 B
  const size_t OFF_ST   = OFF_BAR + 16384;
  const size_t OFF_TH   = OFF_ST + 49152;
  const size_t OFF_MU   = OFF_TH + 819200;
  const size_t OFF_LV   = OFF_MU + 819200;
  const size_t OFF_BIG  = OFF_LV + 819200;
  // phase-1 overlay of BIG
  const size_t OFF_H1   = OFF_BIG;              // 8,192,000
  const size_t OFF_H2   = OFF_H1 + 8192000;     // 8,192,000
  const size_t OFF_DEC  = OFF_H2 + 8192000;     // 16,384,000 (bf16)
  // phase-2 overlay of BIG
  const size_t OFF_NA   = OFF_BIG;
  const size_t OFF_NB   = OFF_NA + 2400000;
  const size_t OFF_KB   = OFF_NB + 2400000;
  const size_t OFF_KT   = OFF_KB + 8388608;
  const size_t OFF_KM   = OFF_KT + 8388608;
  const size_t OFF_AT   = OFF_KM + 8388608;
  const size_t OFF_BT   = OFF_AT + 524288;
  const size_t OFF_VT   = OFF_BT + 524288;
  const size_t OFF_UT   = OFF_VT + 262144;
  const size_t NEED     = OFF_DEC + 16384000;   // ~35.3 MB
  if (ws_size < NEED) return;

  float* ACCp = (float*)(ws + OFF_ACC);
  int*   FLGp = (int*)(ws + OFF_BAR);
  float* STp  = (float*)(ws + OFF_ST);
  float* st_sum = STp, *st_sq = STp + 2048;
  float* mmean = STp + 4096, *mrstd = STp + 6144;
  float* lmean = STp + 8192, *lrstd = STp + 10240;
  float* THp  = (float*)(ws + OFF_TH);
  float* MUp  = (float*)(ws + OFF_MU);
  float* LVp  = (float*)(ws + OFF_LV);
  float* H1p  = (float*)(ws + OFF_H1);
  float* H2p  = (float*)(ws + OFF_H2);
  unsigned short* DECb = (unsigned short*)(ws + OFF_DEC);
  float* NAp  = (float*)(ws + OFF_NA);
  float* NBp  = (float*)(ws + OFF_NB);
  unsigned short* KBp = (unsigned short*)(ws + OFF_KB);
  unsigned short* KTp = (unsigned short*)(ws + OFF_KT);
  unsigned short* KMp = (unsigned short*)(ws + OFF_KM);
  float* ATp  = (float*)(ws + OFF_AT);
  float* BTp  = (float*)(ws + OFF_BT);
  unsigned short* VTp = (unsigned short*)(ws + OFF_VT);
  unsigned short* UTp = (unsigned short*)(ws + OFF_UT);

  hipMemsetAsync(ACCp, 0, 256, stream);
  hipMemsetAsync(FLGp, 0, 16384, stream);

  auto enc_dec = [&](const float* x, const float* eps, const float* W1, const float* b1,
                     const float* W2, const float* b2, const float* Wmu, const float* bmu,
                     const float* Wlv, const float* blv, const float* mbn, const float* lbn,
                     const float* phi, const float* dbn, float* accp) {
    gemm_nn_kern<<<dim3(8, 64), 256, 0, stream>>>(x, W1, b1, H1p, B_N, H_N, V_N, 1, 0);
    gemm_nn_kern<<<dim3(8, 64), 256, 0, stream>>>(H1p, W2, b2, H2p, B_N, H_N, H_N, 1, 0);
    gemm_nn_kern<<<dim3(1, 64), 256, 0, stream>>>(H2p, Wmu, bmu, MUp, B_N, K_N, H_N, 0, 0);
    gemm_nn_kern<<<dim3(1, 64), 256, 0, stream>>>(H2p, Wlv, blv, LVp, B_N, K_N, H_N, 0, 0);
    hipMemsetAsync(st_sum, 0, 2 * 2048 * 4, stream);
    colstats2_kern<<<dim3(1, 16), 256, 0, stream>>>(MUp, K_N, 256, st_sum, st_sq);
    finstats_kern<<<1, 256, 0, stream>>>(st_sum, st_sq, K_N, 1.f / B_N, mmean, mrstd);
    hipMemsetAsync(st_sum, 0, 2 * 2048 * 4, stream);
    colstats2_kern<<<dim3(1, 16), 256, 0, stream>>>(LVp, K_N, 256, st_sum, st_sq);
    finstats_kern<<<1, 256, 0, stream>>>(st_sum, st_sq, K_N, 1.f / B_N, lmean, lrstd);
    reparam_kern<<<B_N / 4, 256, 0, stream>>>(MUp, LVp, mmean, mrstd, lmean, lrstd,
                                              mbn, lbn, eps, THp, accp);
    gemm_nn_kern<<<dim3(32, 64), 256, 0, stream>>>(THp, phi, nullptr, DECb, B_N, V_N, K_N, 0, 1);
    hipMemsetAsync(st_sum, 0, 2 * 2048 * 4, stream);
    colstats2_bf_kern<<<dim3(8, 16), 256, 0, stream>>>(DECb, V_N, 256, st_sum, st_sq);
    finstats_kern<<<8, 256, 0, stream>>>(st_sum, st_sq, V_N, 1.f / B_N, mmean, mrstd);
    decode_rec_kern<<<B_N, 256, 0, stream>>>(DECb, mmean, mrstd, dbn, x, accp);
  };

  enc_dec(x_a, eps_a, W1_a, b1_a, W2_a, b2_a, Wmu_a, bmu_a, Wlv_a, blv_a, mbn_a, lbn_a,
          phi_a, dbn_a, ACCp + 0);
  enc_dec(x_b, eps_b, W1_b, b1_b, W2_b, b2_b, Wmu_b, bmu_b, Wlv_b, blv_b, mbn_b, lbn_b,
          phi_b, dbn_b, ACCp + 1);

  // ---- phase 2: Sinkhorn prep (aliases the H1/H2/DEC region; stream-ordered) ----
  hipMemsetAsync(KBp, 0, (size_t)VP * VP * 2, stream);
  hipMemsetAsync(KTp, 0, (size_t)VP * VP * 2, stream);
  hipMemsetAsync(KMp, 0, (size_t)VP * VP * 2, stream);
  hipMemsetAsync(ATp, 0, (size_t)TP * VP * 4, stream);
  hipMemsetAsync(BTp, 0, (size_t)TP * VP * 4, stream);
  hipMemsetAsync(VTp, 0, (size_t)TP * VP * 2, stream);
  hipMemsetAsync(UTp, 0, (size_t)TP * VP * 2, stream);

  rownorm_kern<<<V_N, 256, 0, stream>>>(bwe_a, NAp);
  rownorm_kern<<<V_N, 256, 0, stream>>>(bwe_b, NBp);
  gemm_nt_cost_kern<<<dim3(32, 32), 256, 0, stream>>>(NAp, NBp, KBp, KTp, KMp);
  topic_softmax_kern<<<K_N, 256, 0, stream>>>(phi_a, ATp);
  topic_softmax_kern<<<K_N, 256, 0, stream>>>(phi_b, BTp);
  vinit_kern<<<(K_N * V_N + 255) / 256, 256, 0, stream>>>(VTp);

  // ---- Sinkhorn main loop: 128 WGs x 256 thr, pipelined coherent loads ----
  sinkhorn_kern<<<dim3(SK_NWG), dim3(256), 0, stream>>>(KBp, KTp, KMp, ATp, BTp,
                                                        VTp, UTp, ACCp, FLGp);

  finalize_kern<<<1, 64, 0, stream>>>(ACCp, out);
  (void)in_sizes; (void)n_in; (void)out_size;
}

// Round 7
// 13418.179 us; speedup vs baseline: 2.4387x; 1.6404x over previous
//
#include <hip/hip_runtime.h>

// Problem dims
#define B_N 4096
#define V_N 2000
#define K_N 50
#define H_N 500
#define E_N 300
#define VP  2048   // padded vocab (mult of 32 for MFMA k)
#define TP  64     // padded topics
#define SK_NWG 128
#define SK_ITER 500
#define SLOT_E (TP * VP)   // ushort elements per rotation slot (256 KB)

typedef short bf16x8 __attribute__((ext_vector_type(8)));
typedef float f32x4n __attribute__((ext_vector_type(4)));

__device__ __forceinline__ unsigned short f2bf(float f) {
  unsigned int x = __float_as_uint(f);
  x = (x + 0x7FFFu + ((x >> 16) & 1u)) >> 16;
  return (unsigned short)x;
}
__device__ __forceinline__ float bf2f(unsigned short h) {
  return __uint_as_float((unsigned int)h << 16);
}
__device__ __forceinline__ float softplusf(float x) {
  return fmaxf(x, 0.f) + log1pf(expf(-fabsf(x)));
}

// Agent-coherent 8B store (write-through to the coherence point). u/v writes
// are tiny (2 per thread per phase) so the non-coalescing cost is negligible.
__device__ __forceinline__ void coh_store8(unsigned short* p, ushort4 val) {
  union { ushort4 s; unsigned long long u; } cvt; cvt.s = val;
  __hip_atomic_store((unsigned long long*)p, cvt.u,
                     __ATOMIC_RELAXED, __HIP_MEMORY_SCOPE_AGENT);
}

// ---------------------------------------------------------------------------
// fp32 tiled GEMM: C = act(A(MxK) @ B(KxN) + bias); act: 0 none, 1 softplus
// ---------------------------------------------------------------------------
__global__ __launch_bounds__(256) void gemm_nn_kern(
    const float* __restrict__ A, const float* __restrict__ Bm,
    const float* __restrict__ bias, void* __restrict__ Cv,
    int M, int N, int Kd, int act, int bf16out) {
  __shared__ float As[16][68];
  __shared__ float Bs[16][68];
  const int tid = threadIdx.x;
  const int tx = tid & 15, ty = tid >> 4;
  const int row0 = (int)blockIdx.y * 64, col0 = (int)blockIdx.x * 64;
  float acc[4][4];
#pragma unroll
  for (int i = 0; i < 4; ++i)
#pragma unroll
    for (int j = 0; j < 4; ++j) acc[i][j] = 0.f;

  for (int k0 = 0; k0 < Kd; k0 += 16) {
#pragma unroll
    for (int i = 0; i < 4; ++i) {
      int id = tid + 256 * i;
      int m = id >> 4, kk = id & 15;
      int gr = row0 + m, gk = k0 + kk;
      As[kk][m] = (gr < M && gk < Kd) ? A[(size_t)gr * Kd + gk] : 0.f;
    }
#pragma unroll
    for (int i = 0; i < 4; ++i) {
      int id = tid + 256 * i;
      int kk = id >> 6, n = id & 63;
      int gk = k0 + kk, gc = col0 + n;
      Bs[kk][n] = (gk < Kd && gc < N) ? Bm[(size_t)gk * N + gc] : 0.f;
    }
    __syncthreads();
#pragma unroll
    for (int kk = 0; kk < 16; ++kk) {
      float4 av = *(const float4*)&As[kk][ty * 4];
      float4 bv = *(const float4*)&Bs[kk][tx * 4];
      float aa[4] = {av.x, av.y, av.z, av.w};
      float bb[4] = {bv.x, bv.y, bv.z, bv.w};
#pragma unroll
      for (int i = 0; i < 4; ++i)
#pragma unroll
        for (int j = 0; j < 4; ++j) acc[i][j] = fmaf(aa[i], bb[j], acc[i][j]);
    }
    __syncthreads();
  }
#pragma unroll
  for (int i = 0; i < 4; ++i) {
    int row = row0 + ty * 4 + i;
    if (row >= M) continue;
#pragma unroll
    for (int j = 0; j < 4; ++j) {
      int col = col0 + tx * 4 + j;
      if (col >= N) continue;
      float v = acc[i][j] + (bias ? bias[col] : 0.f);
      if (act) v = softplusf(v);
      if (bf16out) ((unsigned short*)Cv)[(size_t)row * N + col] = f2bf(v);
      else         ((float*)Cv)[(size_t)row * N + col] = v;
    }
  }
}

// ---------------------------------------------------------------------------
// Column partial sums (BN stats)
// ---------------------------------------------------------------------------
__global__ void colstats2_kern(const float* __restrict__ X, int C, int rowsPer,
                               float* __restrict__ sums, float* __restrict__ sumsq) {
  int c = (int)blockIdx.x * 256 + threadIdx.x;
  if (c >= C) return;
  int r0 = (int)blockIdx.y * rowsPer;
  float s = 0.f, s2 = 0.f;
  for (int r = r0; r < r0 + rowsPer; ++r) {
    float v = X[(size_t)r * C + c];
    s += v; s2 += v * v;
  }
  atomicAdd(&sums[c], s);
  atomicAdd(&sumsq[c], s2);
}

__global__ void colstats2_bf_kern(const unsigned short* __restrict__ X, int C, int rowsPer,
                                  float* __restrict__ sums, float* __restrict__ sumsq) {
  int c = (int)blockIdx.x * 256 + threadIdx.x;
  if (c >= C) return;
  int r0 = (int)blockIdx.y * rowsPer;
  float s = 0.f, s2 = 0.f;
  for (int r = r0; r < r0 + rowsPer; ++r) {
    float v = bf2f(X[(size_t)r * C + c]);
    s += v; s2 += v * v;
  }
  atomicAdd(&sums[c], s);
  atomicAdd(&sumsq[c], s2);
}

__global__ void finstats_kern(const float* __restrict__ sums, const float* __restrict__ sumsq,
                              int C, float invM, float* __restrict__ mean,
                              float* __restrict__ rstd) {
  int c = (int)blockIdx.x * 256 + threadIdx.x;
  if (c >= C) return;
  float mu = sums[c] * invM;
  float var = sumsq[c] * invM - mu * mu;
  mean[c] = mu;
  rstd[c] = rsqrtf(var + 1e-5f);
}

// ---------------------------------------------------------------------------
// BN-apply + reparam + row-softmax(50) -> theta ; accumulate KLD
// ---------------------------------------------------------------------------
__global__ __launch_bounds__(256) void reparam_kern(
    const float* __restrict__ MUp, const float* __restrict__ LVp,
    const float* __restrict__ mmean, const float* __restrict__ mrstd,
    const float* __restrict__ lmean, const float* __restrict__ lrstd,
    const float* __restrict__ mbn, const float* __restrict__ lbn,
    const float* __restrict__ epsb, float* __restrict__ TH,
    float* __restrict__ accp) {
  const int wave = threadIdx.x >> 6, lane = threadIdx.x & 63;
  const int row = (int)blockIdx.x * 4 + wave;
  const bool act = lane < K_N;
  float mu = 0.f, lv = 0.f, z = 0.f;
  size_t base = (size_t)row * K_N + lane;
  if (act) {
    mu = (MUp[base] - mmean[lane]) * mrstd[lane] + mbn[lane];
    lv = (LVp[base] - lmean[lane]) * lrstd[lane] + lbn[lane];
    z = mu + expf(0.5f * lv) * epsb[base];
  }
  float zm = act ? z : -1e30f;
#pragma unroll
  for (int m = 32; m; m >>= 1) zm = fmaxf(zm, __shfl_xor(zm, m));
  float e = act ? expf(z - zm) : 0.f;
  float se = e;
#pragma unroll
  for (int m = 32; m; m >>= 1) se += __shfl_xor(se, m);
  if (act) TH[base] = e / se;
  float kt = 0.f;
  if (act) {
    float var = expf(lv);
    kt = var * (1.f / 0.98f) + mu * mu * (1.f / 0.98f) + logf(0.98f) - lv;
  }
  float sk = kt;
#pragma unroll
  for (int m = 32; m; m >>= 1) sk += __shfl_xor(sk, m);
  if (lane == 0) atomicAdd(accp, 0.5f * (sk - (float)K_N));
}

// ---------------------------------------------------------------------------
// decode: BN-apply + row softmax + rec; one block/row (DEC bf16)
// ---------------------------------------------------------------------------
__global__ __launch_bounds__(256) void decode_rec_kern(
    const unsigned short* __restrict__ DECb, const float* __restrict__ mean,
    const float* __restrict__ rstd, const float* __restrict__ bias,
    const float* __restrict__ X, float* __restrict__ accp) {
  __shared__ float sred[256];
  const int row = (int)blockIdx.x, tid = threadIdx.x;
  const size_t base = (size_t)row * V_N;
  float mx = -1e30f;
  for (int j = tid; j < V_N; j += 256) {
    float y = (bf2f(DECb[base + j]) - mean[j]) * rstd[j] + bias[j];
    mx = fmaxf(mx, y);
  }
  sred[tid] = mx; __syncthreads();
  for (int s = 128; s; s >>= 1) { if (tid < s) sred[tid] = fmaxf(sred[tid], sred[tid + s]); __syncthreads(); }
  mx = sred[0]; __syncthreads();

  float se = 0.f;
  for (int j = tid; j < V_N; j += 256) {
    float y = (bf2f(DECb[base + j]) - mean[j]) * rstd[j] + bias[j];
    se += expf(y - mx);
  }
  sred[tid] = se; __syncthreads();
  for (int s = 128; s; s >>= 1) { if (tid < s) sred[tid] += sred[tid + s]; __syncthreads(); }
  se = sred[0]; __syncthreads();

  float part = 0.f;
  for (int j = tid; j < V_N; j += 256) {
    float y = (bf2f(DECb[base + j]) - mean[j]) * rstd[j] + bias[j];
    float p = expf(y - mx) / se;
    part += X[base + j] * logf(p + 1e-10f);
  }
  sred[tid] = part; __syncthreads();
  for (int s = 128; s; s >>= 1) { if (tid < s) sred[tid] += sred[tid + s]; __syncthreads(); }
  if (tid == 0) atomicAdd(accp, -sred[0]);
}

// ---------------------------------------------------------------------------
// Row L2-normalize (BWE -> na/nb)
// ---------------------------------------------------------------------------
__global__ void rownorm_kern(const float* __restrict__ Xp, float* __restrict__ Yp) {
  __shared__ float sred[256];
  const int row = (int)blockIdx.x, tid = threadIdx.x;
  float s = 0.f;
  for (int j = tid; j < E_N; j += 256) { float v = Xp[(size_t)row * E_N + j]; s += v * v; }
  sred[tid] = s; __syncthreads();
  for (int st = 128; st; st >>= 1) { if (tid < st) sred[tid] += sred[tid + st]; __syncthreads(); }
  float sc = 1.f / fmaxf(sqrtf(sred[0]), 1e-12f);
  for (int j = tid; j < E_N; j += 256) Yp[(size_t)row * E_N + j] = Xp[(size_t)row * E_N + j] * sc;
}

// ---------------------------------------------------------------------------
// M = 1 - na @ nb^T ; writes K=exp(-10M) and K^T as bf16 (VP-strided).
// K*M is NOT materialized: K*M = -0.1 * K * ln(K), recomputed in the final pass.
// ---------------------------------------------------------------------------
__global__ __launch_bounds__(256) void gemm_nt_cost_kern(
    const float* __restrict__ NAp, const float* __restrict__ NBp,
    unsigned short* __restrict__ Kb, unsigned short* __restrict__ KTb) {
  __shared__ float As[16][68];
  __shared__ float Bs[16][68];
  const int tid = threadIdx.x;
  const int tx = tid & 15, ty = tid >> 4;
  const int row0 = (int)blockIdx.y * 64, col0 = (int)blockIdx.x * 64;
  float acc[4][4];
#pragma unroll
  for (int i = 0; i < 4; ++i)
#pragma unroll
    for (int j = 0; j < 4; ++j) acc[i][j] = 0.f;

  for (int e0 = 0; e0 < E_N; e0 += 16) {
#pragma unroll
    for (int i = 0; i < 4; ++i) {
      int id = tid + 256 * i;
      int m = id >> 4, e = id & 15;
      int ge = e0 + e;
      int gr = row0 + m;
      As[e][m] = (gr < V_N && ge < E_N) ? NAp[(size_t)gr * E_N + ge] : 0.f;
      int gc = col0 + m;
      Bs[e][m] = (gc < V_N && ge < E_N) ? NBp[(size_t)gc * E_N + ge] : 0.f;
    }
    __syncthreads();
#pragma unroll
    for (int kk = 0; kk < 16; ++kk) {
      float4 av = *(const float4*)&As[kk][ty * 4];
      float4 bv = *(const float4*)&Bs[kk][tx * 4];
      float aa[4] = {av.x, av.y, av.z, av.w};
      float bb[4] = {bv.x, bv.y, bv.z, bv.w};
#pragma unroll
      for (int i = 0; i < 4; ++i)
#pragma unroll
        for (int j = 0; j < 4; ++j) acc[i][j] = fmaf(aa[i], bb[j], acc[i][j]);
    }
    __syncthreads();
  }
#pragma unroll
  for (int i = 0; i < 4; ++i) {
    int gi = row0 + ty * 4 + i;
    if (gi >= V_N) continue;
#pragma unroll
    for (int j = 0; j < 4; ++j) {
      int gj = col0 + tx * 4 + j;
      if (gj >= V_N) continue;
      float m = 1.f - acc[i][j];
      float kv = expf(-10.f * m);
      Kb[(size_t)gi * VP + gj] = f2bf(kv);
      KTb[(size_t)gj * VP + gi] = f2bf(kv);
    }
  }
}

// ---------------------------------------------------------------------------
// a/b marginals: softmax over vocab of phi row t (f32, VP-strided)
// ---------------------------------------------------------------------------
__global__ void topic_softmax_kern(const float* __restrict__ phi, float* __restrict__ ATp) {
  __shared__ float sred[256];
  const int t = (int)blockIdx.x, tid = threadIdx.x;
  const size_t base = (size_t)t * V_N;
  float mx = -1e30f;
  for (int i = tid; i < V_N; i += 256) mx = fmaxf(mx, phi[base + i]);
  sred[tid] = mx; __syncthreads();
  for (int s = 128; s; s >>= 1) { if (tid < s) sred[tid] = fmaxf(sred[tid], sred[tid + s]); __syncthreads(); }
  mx = sred[0]; __syncthreads();
  float se = 0.f;
  for (int i = tid; i < V_N; i += 256) se += expf(phi[base + i] - mx);
  sred[tid] = se; __syncthreads();
  for (int s = 128; s; s >>= 1) { if (tid < s) sred[tid] += sred[tid + s]; __syncthreads(); }
  se = sred[0];
  for (int i = tid; i < V_N; i += 256) ATp[(size_t)t * VP + i] = expf(phi[base + i] - mx) / se;
}

__global__ void vinit_kern(unsigned short* __restrict__ VTp) {
  int id = (int)blockIdx.x * 256 + threadIdx.x;
  if (id >= K_N * V_N) return;
  int t = id / V_N, i = id - t * V_N;
  VTp[(size_t)t * VP + i] = f2bf(1.0f / (float)V_N);
}

__global__ void finalize_kern(const float* __restrict__ accp, float* __restrict__ out) {
  if (threadIdx.x == 0)
    out[0] = (accp[0] + accp[1]) * (1.f / (float)B_N) + 0.1f * accp[2];
}

// ---------------------------------------------------------------------------
// Sinkhorn: 500 iters of u=a/(Kv), v=b/(K^T u), then transport cost.
// KEY CHANGE (R7): u/v live in a 32-slot ROTATION (8 MB). Producers store
// coherently (write-through, tiny); consumers use PLAIN CACHED bf16x8 loads —
// full coalescing + per-XCD L2 sharing. Agent-scope atomic loads were the
// R2-R6 wall (~8 B/cyc/CU, non-coalescing). Staleness is impossible in
// practice: a slot is reused only after 31x256KB (7.75 MB) has streamed
// through the 4 MB per-XCD L2 (32 KB L1), evicting any old copy by capacity.
// Fence-free flag barrier unchanged (validated R2-R6, absmax 0).
// ---------------------------------------------------------------------------
__device__ __forceinline__ void gbar(int* flags, int epoch, int wg, int tid) {
  __syncthreads();  // all waves arrived; per-wave vmcnt(0) drained (coh stores at IF)
  if (tid == 0)
    __hip_atomic_store(&flags[wg * 32], epoch, __ATOMIC_RELAXED, __HIP_MEMORY_SCOPE_AGENT);
  {
    int* line = &flags[(tid & (SK_NWG - 1)) * 32];
    int spin = 0;
    while (__hip_atomic_load(line, __ATOMIC_RELAXED, __HIP_MEMORY_SCOPE_AGENT) < epoch) {
      __builtin_amdgcn_s_sleep(1);
      if (++spin >= (1 << 17)) break;  // bounded: desync -> wrong answer, not hang
    }
  }
  __syncthreads();
}

// MFMA sweep: this wave's 512-col k-slice partials for 16 rows x 64 topics.
// A (K rows) and B (u/v) are both PLAIN loads now.
__device__ __forceinline__ void sk_mm16(
    const unsigned short* __restrict__ Mat, const unsigned short* __restrict__ Xt,
    float* __restrict__ red, int wg, int wave, int lane) {
  const int m = lane & 15, q = lane >> 4;
  const unsigned short* arow = Mat + (size_t)(wg * 16 + m) * VP + wave * 512 + q * 8;
  const unsigned short* xrow = Xt + (size_t)m * VP + wave * 512 + q * 8;
  bf16x8 Af[16];
#pragma unroll
  for (int ks = 0; ks < 16; ++ks) Af[ks] = *(const bf16x8*)(arow + ks * 32);
#pragma unroll
  for (int t = 0; t < 4; ++t) {
    f32x4n a = (f32x4n){0.f, 0.f, 0.f, 0.f};
#pragma unroll
    for (int ks = 0; ks < 16; ++ks) {
      bf16x8 bv = *(const bf16x8*)(xrow + (size_t)t * (16 * VP) + ks * 32);
      a = __builtin_amdgcn_mfma_f32_16x16x32_bf16(Af[ks], bv, a, 0, 0, 0);
    }
    *(f32x4n*)&red[wave * 1280 + (t * 16 + m) * 20 + q * 4] = a;
  }
}

// Same sweep but A = -0.1 * K * ln(K) computed on the fly from Kb (final pass).
__device__ __forceinline__ void sk_mm16_km(
    const unsigned short* __restrict__ Mat, const unsigned short* __restrict__ Xt,
    float* __restrict__ red, int wg, int wave, int lane) {
  const int m = lane & 15, q = lane >> 4;
  const unsigned short* arow = Mat + (size_t)(wg * 16 + m) * VP + wave * 512 + q * 8;
  const unsigned short* xrow = Xt + (size_t)m * VP + wave * 512 + q * 8;
  bf16x8 Af[16];
#pragma unroll
  for (int ks = 0; ks < 16; ++ks) {
    union { bf16x8 v; unsigned short s[8]; } a, o;
    a.v = *(const bf16x8*)(arow + ks * 32);
#pragma unroll
    for (int e = 0; e < 8; ++e) {
      float k = bf2f(a.s[e]);
      o.s[e] = (k > 0.f) ? f2bf(-0.1f * k * logf(k)) : (unsigned short)0;
    }
    Af[ks] = o.v;
  }
#pragma unroll
  for (int t = 0; t < 4; ++t) {
    f32x4n a = (f32x4n){0.f, 0.f, 0.f, 0.f};
#pragma unroll
    for (int ks = 0; ks < 16; ++ks) {
      bf16x8 bv = *(const bf16x8*)(xrow + (size_t)t * (16 * VP) + ks * 32);
      a = __builtin_amdgcn_mfma_f32_16x16x32_bf16(Af[ks], bv, a, 0, 0, 0);
    }
    *(f32x4n*)&red[wave * 1280 + (t * 16 + m) * 20 + q * 4] = a;
  }
}

__device__ __forceinline__ void sk_phase(
    const unsigned short* __restrict__ Mat, const unsigned short* __restrict__ Xt,
    const float* __restrict__ Ap, unsigned short* __restrict__ Outp,
    float* red, int wg, int wave, int lane, int tid) {
  sk_mm16(Mat, Xt, red, wg, wave, lane);
  __syncthreads();
  {
    const int c = tid >> 2, r0 = (tid & 3) * 4;   // c: topic 0..63, r0: row-group
    f32x4n s = (f32x4n){0.f, 0.f, 0.f, 0.f};
#pragma unroll
    for (int w = 0; w < 4; ++w) s += *(const f32x4n*)&red[w * 1280 + c * 20 + r0];
    f32x4n a4 = *(const f32x4n*)(Ap + (size_t)c * VP + wg * 16 + r0);
    f32x4n u = a4 / (s + 1e-16f);
    ushort4 ub;
    ub.x = f2bf(u.x); ub.y = f2bf(u.y); ub.z = f2bf(u.z); ub.w = f2bf(u.w);
    coh_store8(Outp + (size_t)c * VP + wg * 16 + r0, ub);
  }
  __syncthreads();
}

__global__ void __launch_bounds__(256, 1) sinkhorn_kern(
    const unsigned short* __restrict__ Kb, const unsigned short* __restrict__ KTb,
    const float* __restrict__ ATp, const float* __restrict__ BTp,
    unsigned short* __restrict__ ROTp, float* __restrict__ accp,
    int* __restrict__ flags) {
  __shared__ float red[5120];
  const int wg = (int)blockIdx.x, tid = threadIdx.x;
  const int wave = tid >> 6, lane = tid & 63;

  for (int ph = 0; ph < 2 * SK_ITER; ++ph) {
    const unsigned short* src = ROTp + (size_t)((ph + 31) & 31) * SLOT_E;
    unsigned short* dst = ROTp + (size_t)(ph & 31) * SLOT_E;
    if ((ph & 1) == 0) sk_phase(Kb, src, ATp, dst, red, wg, wave, lane, tid);
    else               sk_phase(KTb, src, BTp, dst, red, wg, wave, lane, tid);
    gbar(flags, ph + 1, wg, tid);
  }

  // final: u = a/(K v + eps); s_loss = sum u * ((K*M) v), K*M = -0.1 K lnK
  const unsigned short* vfin = ROTp + (size_t)((2 * SK_ITER - 1) & 31) * SLOT_E;
  const int c = tid >> 2, r0 = (tid & 3) * 4;
  float u4[4];

  sk_mm16(Kb, vfin, red, wg, wave, lane);
  __syncthreads();
  {
    f32x4n s = (f32x4n){0.f, 0.f, 0.f, 0.f};
#pragma unroll
    for (int w = 0; w < 4; ++w) s += *(const f32x4n*)&red[w * 1280 + c * 20 + r0];
    f32x4n a4 = *(const f32x4n*)(ATp + (size_t)c * VP + wg * 16 + r0);
#pragma unroll
    for (int i = 0; i < 4; ++i) u4[i] = a4[i] / (s[i] + 1e-16f);
  }
  __syncthreads();
  sk_mm16_km(Kb, vfin, red, wg, wave, lane);
  __syncthreads();
  float part = 0.f;
  {
    f32x4n s = (f32x4n){0.f, 0.f, 0.f, 0.f};
#pragma unroll
    for (int w = 0; w < 4; ++w) s += *(const f32x4n*)&red[w * 1280 + c * 20 + r0];
#pragma unroll
    for (int i = 0; i < 4; ++i) part += u4[i] * s[i];
  }
  __syncthreads();
  red[tid] = part; __syncthreads();
  for (int st = 128; st; st >>= 1) { if (tid < st) red[tid] += red[tid + st]; __syncthreads(); }
  if (tid == 0) atomicAdd(accp + 2, red[0]);
}

// ---------------------------------------------------------------------------
extern "C" void kernel_launch(void* const* d_in, const int* in_sizes, int n_in,
                              void* d_out, int out_size, void* d_ws, size_t ws_size,
                              hipStream_t stream) {
  const float* x_a   = (const float*)d_in[0];
  const float* x_b   = (const float*)d_in[1];
  const float* eps_a = (const float*)d_in[2];
  const float* eps_b = (const float*)d_in[3];
  const float* W1_a  = (const float*)d_in[4];
  const float* b1_a  = (const float*)d_in[5];
  const float* W2_a  = (const float*)d_in[6];
  const float* b2_a  = (const float*)d_in[7];
  const float* Wmu_a = (const float*)d_in[8];
  const float* bmu_a = (const float*)d_in[9];
  const float* Wlv_a = (const float*)d_in[10];
  const float* blv_a = (const float*)d_in[11];
  const float* mbn_a = (const float*)d_in[12];
  const float* lbn_a = (const float*)d_in[13];
  const float* W1_b  = (const float*)d_in[14];
  const float* b1_b  = (const float*)d_in[15];
  const float* W2_b  = (const float*)d_in[16];
  const float* b2_b  = (const float*)d_in[17];
  const float* Wmu_b = (const float*)d_in[18];
  const float* bmu_b = (const float*)d_in[19];
  const float* Wlv_b = (const float*)d_in[20];
  const float* blv_b = (const float*)d_in[21];
  const float* mbn_b = (const float*)d_in[22];
  const float* lbn_b = (const float*)d_in[23];
  const float* dbn_a = (const float*)d_in[24];
  const float* dbn_b = (const float*)d_in[25];
  const float* phi_a = (const float*)d_in[26];
  const float* phi_b = (const float*)d_in[27];
  const float* bwe_a = (const float*)d_in[28];
  const float* bwe_b = (const float*)d_in[29];
  float* out = (float*)d_out;

  // ---- static workspace layout with phase aliasing (~35.3 MB total) ----
  char* ws = (char*)d_ws;
  const size_t OFF_ACC  = 0;                    // 256 B
  const size_t OFF_BAR  = 256;                  // flags: 128 lines x 128 B
  const size_t OFF_ST   = OFF_BAR + 16384;
  const size_t OFF_TH   = OFF_ST + 49152;
  const size_t OFF_MU   = OFF_TH + 819200;
  const size_t OFF_LV   = OFF_MU + 819200;
  const size_t OFF_BIG  = OFF_LV + 819200;
  // phase-1 overlay of BIG (32.77 MB)
  const size_t OFF_H1   = OFF_BIG;              // 8,192,000
  const size_t OFF_H2   = OFF_H1 + 8192000;     // 8,192,000
  const size_t OFF_DEC  = OFF_H2 + 8192000;     // 16,384,000 (bf16)
  // phase-2 overlay of BIG (31.0 MB)
  const size_t OFF_NA   = OFF_BIG;              // 2,400,000
  const size_t OFF_NB   = OFF_NA + 2400000;     // 2,400,000
  const size_t OFF_KB   = OFF_NB + 2400000;     // 8,388,608
  const size_t OFF_KT   = OFF_KB + 8388608;     // 8,388,608
  const size_t OFF_AT   = OFF_KT + 8388608;     // 524,288
  const size_t OFF_BT   = OFF_AT + 524288;      // 524,288
  const size_t OFF_ROT  = OFF_BT + 524288;      // 32 x 262,144 = 8,388,608
  const size_t NEED     = OFF_DEC + 16384000;   // ~35.3 MB (phase-1 bound)
  if (ws_size < NEED) return;

  float* ACCp = (float*)(ws + OFF_ACC);
  int*   FLGp = (int*)(ws + OFF_BAR);
  float* STp  = (float*)(ws + OFF_ST);
  float* st_sum = STp, *st_sq = STp + 2048;
  float* mmean = STp + 4096, *mrstd = STp + 6144;
  float* lmean = STp + 8192, *lrstd = STp + 10240;
  float* THp  = (float*)(ws + OFF_TH);
  float* MUp  = (float*)(ws + OFF_MU);
  float* LVp  = (float*)(ws + OFF_LV);
  float* H1p  = (float*)(ws + OFF_H1);
  float* H2p  = (float*)(ws + OFF_H2);
  unsigned short* DECb = (unsigned short*)(ws + OFF_DEC);
  float* NAp  = (float*)(ws + OFF_NA);
  float* NBp  = (float*)(ws + OFF_NB);
  unsigned short* KBp = (unsigned short*)(ws + OFF_KB);
  unsigned short* KTp = (unsigned short*)(ws + OFF_KT);
  float* ATp  = (float*)(ws + OFF_AT);
  float* BTp  = (float*)(ws + OFF_BT);
  unsigned short* ROTp = (unsigned short*)(ws + OFF_ROT);
  unsigned short* SLOT31 = ROTp + (size_t)31 * SLOT_E;

  hipMemsetAsync(ACCp, 0, 256, stream);
  hipMemsetAsync(FLGp, 0, 16384, stream);

  auto enc_dec = [&](const float* x, const float* eps, const float* W1, const float* b1,
                     const float* W2, const float* b2, const float* Wmu, const float* bmu,
                     const float* Wlv, const float* blv, const float* mbn, const float* lbn,
                     const float* phi, const float* dbn, float* accp) {
    gemm_nn_kern<<<dim3(8, 64), 256, 0, stream>>>(x, W1, b1, H1p, B_N, H_N, V_N, 1, 0);
    gemm_nn_kern<<<dim3(8, 64), 256, 0, stream>>>(H1p, W2, b2, H2p, B_N, H_N, H_N, 1, 0);
    gemm_nn_kern<<<dim3(1, 64), 256, 0, stream>>>(H2p, Wmu, bmu, MUp, B_N, K_N, H_N, 0, 0);
    gemm_nn_kern<<<dim3(1, 64), 256, 0, stream>>>(H2p, Wlv, blv, LVp, B_N, K_N, H_N, 0, 0);
    hipMemsetAsync(st_sum, 0, 2 * 2048 * 4, stream);
    colstats2_kern<<<dim3(1, 16), 256, 0, stream>>>(MUp, K_N, 256, st_sum, st_sq);
    finstats_kern<<<1, 256, 0, stream>>>(st_sum, st_sq, K_N, 1.f / B_N, mmean, mrstd);
    hipMemsetAsync(st_sum, 0, 2 * 2048 * 4, stream);
    colstats2_kern<<<dim3(1, 16), 256, 0, stream>>>(LVp, K_N, 256, st_sum, st_sq);
    finstats_kern<<<1, 256, 0, stream>>>(st_sum, st_sq, K_N, 1.f / B_N, lmean, lrstd);
    reparam_kern<<<B_N / 4, 256, 0, stream>>>(MUp, LVp, mmean, mrstd, lmean, lrstd,
                                              mbn, lbn, eps, THp, accp);
    gemm_nn_kern<<<dim3(32, 64), 256, 0, stream>>>(THp, phi, nullptr, DECb, B_N, V_N, K_N, 0, 1);
    hipMemsetAsync(st_sum, 0, 2 * 2048 * 4, stream);
    colstats2_bf_kern<<<dim3(8, 16), 256, 0, stream>>>(DECb, V_N, 256, st_sum, st_sq);
    finstats_kern<<<8, 256, 0, stream>>>(st_sum, st_sq, V_N, 1.f / B_N, mmean, mrstd);
    decode_rec_kern<<<B_N, 256, 0, stream>>>(DECb, mmean, mrstd, dbn, x, accp);
  };

  enc_dec(x_a, eps_a, W1_a, b1_a, W2_a, b2_a, Wmu_a, bmu_a, Wlv_a, blv_a, mbn_a, lbn_a,
          phi_a, dbn_a, ACCp + 0);
  enc_dec(x_b, eps_b, W1_b, b1_b, W2_b, b2_b, Wmu_b, bmu_b, Wlv_b, blv_b, mbn_b, lbn_b,
          phi_b, dbn_b, ACCp + 1);

  // ---- phase 2: Sinkhorn prep (aliases the H1/H2/DEC region; stream-ordered) ----
  hipMemsetAsync(KBp, 0, (size_t)VP * VP * 2, stream);
  hipMemsetAsync(KTp, 0, (size_t)VP * VP * 2, stream);
  hipMemsetAsync(ATp, 0, (size_t)TP * VP * 4, stream);
  hipMemsetAsync(BTp, 0, (size_t)TP * VP * 4, stream);
  hipMemsetAsync(SLOT31, 0, (size_t)SLOT_E * 2, stream);   // initial v slot (pads = 0)

  rownorm_kern<<<V_N, 256, 0, stream>>>(bwe_a, NAp);
  rownorm_kern<<<V_N, 256, 0, stream>>>(bwe_b, NBp);
  gemm_nt_cost_kern<<<dim3(32, 32), 256, 0, stream>>>(NAp, NBp, KBp, KTp);
  topic_softmax_kern<<<K_N, 256, 0, stream>>>(phi_a, ATp);
  topic_softmax_kern<<<K_N, 256, 0, stream>>>(phi_b, BTp);
  vinit_kern<<<(K_N * V_N + 255) / 256, 256, 0, stream>>>(SLOT31);

  // ---- Sinkhorn main loop: rotating slots + plain cached v loads ----
  sinkhorn_kern<<<dim3(SK_NWG), dim3(256), 0, stream>>>(KBp, KTp, ATp, BTp,
                                                        ROTp, ACCp, FLGp);

  finalize_kern<<<1, 64, 0, stream>>>(ACCp, out);
  (void)in_sizes; (void)n_in; (void)out_size;
}